// Round 1
// baseline (759.089 us; speedup 1.0000x reference)
//
#include <hip/hip_runtime.h>
#include <hip/hip_bf16.h>

#define TT   4096
#define HH   1024
#define FF   3584
#define EE   8
#define N13  7168   // 2*FF (interleaved w1/w3 at 16-col granularity)
#define TKP  8192   // TT * top_k

typedef unsigned short u16;
typedef __attribute__((ext_vector_type(8))) short short8;
typedef __attribute__((ext_vector_type(4))) float floatx4;

__device__ __forceinline__ u16 f2b(float f) {
  union { float f; unsigned u; } v; v.f = f;
  unsigned r = v.u + 0x7FFFu + ((v.u >> 16) & 1u);   // RNE
  return (u16)(r >> 16);
}

// async global->LDS, 16 bytes per lane. LDS dst semantics: wave-uniform base
// + lane*16; our per-lane dst pointer equals exactly that.
__device__ __forceinline__ void gld_lds16(const u16* g, u16* l) {
  __builtin_amdgcn_global_load_lds((const __attribute__((address_space(1))) unsigned int*)g,
                                   (__attribute__((address_space(3))) unsigned int*)l,
                                   16, 0, 0);
}

#define WAIT_LGKM0() asm volatile("s_waitcnt lgkmcnt(0)" ::: "memory")
#define WAIT_VM(n)   asm volatile("s_waitcnt vmcnt(" #n ")" ::: "memory")
#define BARRIER()    do { asm volatile("" ::: "memory"); __builtin_amdgcn_s_barrier(); asm volatile("" ::: "memory"); } while (0)

// ---------------- conversions ----------------
// w13i[e][n][h]: n -> f=(n>>5)*16+(n&15), sel=(n>>4)&1 ; sel=0 -> w1[e][f], sel=1 -> w3[e][f]
__global__ __launch_bounds__(256) void cvt_w13(const float* __restrict__ w1, const float* __restrict__ w3,
                                               ushort4* __restrict__ w13i) {
  int i = blockIdx.x * 256 + threadIdx.x;      // float4 index in dest
  const int perE = N13 * (HH / 4);
  int e = i / perE;
  int rem = i - e * perE;
  int n = rem / (HH / 4);
  int h4 = rem - n * (HH / 4);
  int f = ((n >> 5) << 4) + (n & 15);
  int sel = (n >> 4) & 1;
  const float* base = sel ? w3 : w1;
  const float4* src = ((const float4*)(base + (size_t)(e * FF + f) * HH)) + h4;
  float4 v = *src;
  ushort4 o; o.x = f2b(v.x); o.y = f2b(v.y); o.z = f2b(v.z); o.w = f2b(v.w);
  w13i[i] = o;
}

__global__ __launch_bounds__(256) void cvt_w2(const float4* __restrict__ in, ushort4* __restrict__ outp) {
  int i = blockIdx.x * 256 + threadIdx.x;
  float4 v = in[i];
  ushort4 o; o.x = f2b(v.x); o.y = f2b(v.y); o.z = f2b(v.z); o.w = f2b(v.w);
  outp[i] = o;
}

// ---------------- router (fused x->bf16 conversion) ----------------
__global__ __launch_bounds__(256) void router(const float* __restrict__ x, const float* __restrict__ gw,
                                              int* __restrict__ cnt, int* __restrict__ tok_list,
                                              float* __restrict__ wt_list, u16* __restrict__ xb) {
  int lane = threadIdx.x & 63;
  int wv = threadIdx.x >> 6;
  int t = blockIdx.x * 4 + wv;
  const float* xp = x + (size_t)t * HH;
  u16* xbp = xb + (size_t)t * HH;
  float acc[EE];
#pragma unroll
  for (int e = 0; e < EE; e++) acc[e] = 0.f;
  for (int h = lane; h < HH; h += 64) {
    float xv = xp[h];
    xbp[h] = f2b(xv);
#pragma unroll
    for (int e = 0; e < EE; e++) acc[e] += xv * gw[e * HH + h];
  }
#pragma unroll
  for (int e = 0; e < EE; e++) {
#pragma unroll
    for (int off = 32; off > 0; off >>= 1) acc[e] += __shfl_xor(acc[e], off, 64);
  }
  if (lane == 0) {
    int i1 = 0;
#pragma unroll
    for (int e = 1; e < EE; e++) if (acc[e] > acc[i1]) i1 = e;
    int i2 = -1;
#pragma unroll
    for (int e = 0; e < EE; e++) {
      if (e == i1) continue;
      if (i2 < 0 || acc[e] > acc[i2]) i2 = e;
    }
    float wA = 1.f / (1.f + __expf(acc[i2] - acc[i1]));
    float wB = 1.f - wA;
    int p1 = atomicAdd(cnt + i1, 1);
    tok_list[i1 * TT + p1] = t; wt_list[i1 * TT + p1] = wA;
    int p2 = atomicAdd(cnt + i2, 1);
    tok_list[i2 * TT + p2] = t; wt_list[i2 * TT + p2] = wB;
  }
}

__global__ void mk_offsets(const int* __restrict__ cnt, int* __restrict__ offs) {
  if (threadIdx.x == 0) {
    int s = 0;
    for (int e = 0; e < EE; e++) { offs[e] = s; s += cnt[e]; }
  }
}

__global__ __launch_bounds__(256) void pairmap(const int* __restrict__ cnt, const int* __restrict__ offs,
                                               const int* __restrict__ tok_list,
                                               int* __restrict__ tokp) {
  int i = blockIdx.x * 256 + threadIdx.x;   // e*TT + s
  int e = i >> 12;
  int s = i & (TT - 1);
  if (s < cnt[e]) {
    tokp[offs[e] + s] = tok_list[i];
  }
}

// ---------------- GEMM A + fused SwiGLU ----------------
// 256x256 tile, BK=64, 8 waves (2Mx4N), per-wave 128x64 C.
// Double-buffered LDS, counted vmcnt(8) pipeline (prefetch distance 2 K-tiles).
// g[pair][f] = silu(x.w1[f]) * (x.w3[f]) * route_wt
__global__ __launch_bounds__(512, 2) void gemm_a(const u16* __restrict__ xb, const u16* __restrict__ w13i,
                                                 const int* __restrict__ cnt, const int* __restrict__ offs,
                                                 const int* __restrict__ tok_list, const float* __restrict__ wt_list,
                                                 u16* __restrict__ gbuf) {
  // bijective XCD swizzle: nwg = 28*128 = 3584, 448 per XCD
  const int fid = blockIdx.y * 28 + blockIdx.x;
  const int swz = (fid & 7) * 448 + (fid >> 3);
  const int ntile = swz % 28;              // 0..27 (128 f-values each)
  const int yy = swz / 28;
  const int e = yy >> 4;
  const int rt = yy & 15;
  const int cn = cnt[e];
  if (rt * 256 >= cn) return;

  extern __shared__ char dynsmem[];
  u16* As = (u16*)dynsmem;                         // [2][256*64]
  u16* Bs = (u16*)(dynsmem + 65536);               // [2][256*64]
  int* toks = (int*)(dynsmem + 131072);            // [256]
  float* wts = (float*)(dynsmem + 131072 + 1024);  // [256]

  const int tid = threadIdx.x;
  if (tid < 256) {
    int r = rt * 256 + tid;
    if (r >= cn) r = cn - 1;
    toks[tid] = tok_list[e * TT + r];
    wts[tid] = wt_list[e * TT + r];
  }
  __syncthreads();

  // staging: round i covers rows (tid>>3)+i*64; 8 lanes per row, each 16B.
  // XOR swizzle at 16B granule: phys granule (tid&7) holds logical
  // l = (tid&7) ^ (row&7); row&7 == (tid>>3)&7 for all rounds.
  const int l = (tid & 7) ^ ((tid >> 3) & 7);
  const int dst0 = tid * 8;
  const u16* aS[4];
  const u16* bS[4];
#pragma unroll
  for (int i = 0; i < 4; i++) {
    int row = (tid >> 3) + i * 64;
    aS[i] = xb + (size_t)toks[row] * HH + l * 8;
    bS[i] = w13i + ((size_t)e * N13 + (size_t)ntile * 256 + row) * HH + l * 8;
  }

  auto STAGE = [&](int kt) {
    int b = (kt & 1) * 16384;
#pragma unroll
    for (int i = 0; i < 4; i++) {
      gld_lds16(aS[i] + kt * 64, As + b + dst0 + i * 4096);
      gld_lds16(bS[i] + kt * 64, Bs + b + dst0 + i * 4096);
    }
  };

  const int lane = tid & 63;
  const int wv = tid >> 6;
  const int wr = (wv >> 2) * 128;
  const int wc = (wv & 3) * 64;
  const int fr = lane & 15;
  const int fk8 = lane >> 4;                // k-granule sub-index (0..3)

  floatx4 acc[8][4];
#pragma unroll
  for (int mi = 0; mi < 8; mi++)
#pragma unroll
    for (int ni = 0; ni < 4; ni++)
#pragma unroll
      for (int q = 0; q < 4; q++) acc[mi][ni][q] = 0.f;

  // prologue: fill both buffers, wait for K-tile 0 only
  STAGE(0);
  STAGE(1);
  WAIT_VM(8);
  BARRIER();

  for (int t = 0; t < 16; t++) {
    const u16* Ab = As + (t & 1) * 16384;
    const u16* Bb = Bs + (t & 1) * 16384;
    __builtin_amdgcn_s_setprio(1);
#pragma unroll
    for (int ks = 0; ks < 2; ks++) {
      const int co = ((ks * 4 + fk8) ^ (fr & 7)) * 8;   // de-swizzled 16B granule
      short8 af[8];
#pragma unroll
      for (int mi = 0; mi < 8; mi++)
        af[mi] = *(const short8*)&Ab[(wr + mi * 16 + fr) * 64 + co];
#pragma unroll
      for (int ni = 0; ni < 4; ni++) {
        short8 bf = *(const short8*)&Bb[(wc + ni * 16 + fr) * 64 + co];
#pragma unroll
        for (int mi = 0; mi < 8; mi++)
          acc[mi][ni] = __builtin_amdgcn_mfma_f32_16x16x32_bf16(af[mi], bf, acc[mi][ni], 0, 0, 0);
      }
    }
    __builtin_amdgcn_s_setprio(0);
    // all reads of buf[t&1] done -> safe to overwrite after the barrier
    WAIT_LGKM0();
    BARRIER();
    if (t + 2 < 16) {
      STAGE(t + 2);
      WAIT_VM(8);        // K-tile t+1 landed; t+2's 8 loads stay in flight
    } else {
      WAIT_VM(0);        // tail: drain everything
    }
    BARRIER();
  }

  // fused SwiGLU epilogue: cols (2pg, 2pg+1) are the (w1,w3) pair for
  // f = ntile*128 + wc/2 + pg*16 + (lane&15)
  const int gofs = offs[e];
  const int cl = lane & 15;
  const int qr = (lane >> 4) * 4;
#pragma unroll
  for (int mi = 0; mi < 8; mi++) {
#pragma unroll
    for (int q = 0; q < 4; q++) {
      int r = wr + mi * 16 + qr + q;
      int gr = rt * 256 + r;
      if (gr < cn) {
        float w = wts[r];
        u16* dst = gbuf + (size_t)(gofs + gr) * FF + (size_t)ntile * 128 + (wc >> 1) + cl;
#pragma unroll
        for (int pg = 0; pg < 2; pg++) {
          float h1 = acc[mi][2 * pg][q];
          float h3 = acc[mi][2 * pg + 1][q];
          float s = h1 / (1.f + __expf(-h1));
          dst[pg * 16] = f2b(s * h3 * w);
        }
      }
    }
  }
}

// ---------------- GEMM B: out[tok] += g[pair] . w2[e][h][:] ----------------
// 256x128 tile, BK=64, 8 waves (4Mx2N), per-wave 64x64 C. Same pipeline, vmcnt(6).
__global__ __launch_bounds__(512, 2) void gemm_b(const u16* __restrict__ g, const u16* __restrict__ w2b,
                                                 const int* __restrict__ cnt, const int* __restrict__ offs,
                                                 const int* __restrict__ tokp, float* __restrict__ out) {
  // bijective XCD swizzle: nwg = 8*128 = 1024, 128 per XCD
  const int fid = blockIdx.y * 8 + blockIdx.x;
  const int swz = (fid & 7) * 128 + (fid >> 3);
  const int ntile = swz % 8;               // 0..7 (128 h-values each)
  const int yy = swz / 8;
  const int e = yy >> 4;
  const int rt = yy & 15;
  const int cn = cnt[e];
  if (rt * 256 >= cn) return;
  const int gofs = offs[e];

  extern __shared__ char dynsmem[];
  u16* As = (u16*)dynsmem;                  // [2][256*64]
  u16* Bs = (u16*)(dynsmem + 65536);        // [2][128*64]
  int* toks = (int*)(dynsmem + 65536 + 32768);

  const int tid = threadIdx.x;
  if (tid < 256) {
    int r = rt * 256 + tid;
    if (r >= cn) r = cn - 1;
    toks[tid] = tokp[gofs + r];
  }
  __syncthreads();

  const int l = (tid & 7) ^ ((tid >> 3) & 7);
  const int dst0 = tid * 8;
  const u16* aS[4];
  const u16* bS[2];
#pragma unroll
  for (int i = 0; i < 4; i++) {
    int row = (tid >> 3) + i * 64;
    int gr = rt * 256 + row;
    if (gr >= cn) gr = cn - 1;
    aS[i] = g + (size_t)(gofs + gr) * FF + l * 8;
  }
#pragma unroll
  for (int i = 0; i < 2; i++) {
    int row = (tid >> 3) + i * 64;
    bS[i] = w2b + ((size_t)e * HH + (size_t)ntile * 128 + row) * FF + l * 8;
  }

  auto STAGE = [&](int kt) {
    int ba = (kt & 1) * 16384;
    int bb = (kt & 1) * 8192;
#pragma unroll
    for (int i = 0; i < 4; i++) gld_lds16(aS[i] + kt * 64, As + ba + dst0 + i * 4096);
#pragma unroll
    for (int i = 0; i < 2; i++) gld_lds16(bS[i] + kt * 64, Bs + bb + dst0 + i * 4096);
  };

  const int lane = tid & 63;
  const int wv = tid >> 6;
  const int wr = (wv >> 1) * 64;
  const int wc = (wv & 1) * 64;
  const int fr = lane & 15;
  const int fk8 = lane >> 4;

  floatx4 acc[4][4];
#pragma unroll
  for (int mi = 0; mi < 4; mi++)
#pragma unroll
    for (int ni = 0; ni < 4; ni++)
#pragma unroll
      for (int q = 0; q < 4; q++) acc[mi][ni][q] = 0.f;

  STAGE(0);
  STAGE(1);
  WAIT_VM(6);
  BARRIER();

  for (int t = 0; t < 56; t++) {
    const u16* Ab = As + (t & 1) * 16384;
    const u16* Bb = Bs + (t & 1) * 8192;
    __builtin_amdgcn_s_setprio(1);
#pragma unroll
    for (int ks = 0; ks < 2; ks++) {
      const int co = ((ks * 4 + fk8) ^ (fr & 7)) * 8;
      short8 af[4];
#pragma unroll
      for (int mi = 0; mi < 4; mi++)
        af[mi] = *(const short8*)&Ab[(wr + mi * 16 + fr) * 64 + co];
#pragma unroll
      for (int ni = 0; ni < 4; ni++) {
        short8 bf = *(const short8*)&Bb[(wc + ni * 16 + fr) * 64 + co];
#pragma unroll
        for (int mi = 0; mi < 4; mi++)
          acc[mi][ni] = __builtin_amdgcn_mfma_f32_16x16x32_bf16(af[mi], bf, acc[mi][ni], 0, 0, 0);
      }
    }
    __builtin_amdgcn_s_setprio(0);
    WAIT_LGKM0();
    BARRIER();
    if (t + 2 < 56) {
      STAGE(t + 2);
      WAIT_VM(6);
    } else {
      WAIT_VM(0);
    }
    BARRIER();
  }

  const int cl = lane & 15;
  const int qr = (lane >> 4) * 4;
#pragma unroll
  for (int mi = 0; mi < 4; mi++) {
#pragma unroll
    for (int q = 0; q < 4; q++) {
      int r = wr + mi * 16 + qr + q;
      int gr = rt * 256 + r;
      if (gr < cn) {
        int tk = toks[r];
        float* dst = out + (size_t)tk * HH + (size_t)ntile * 128 + wc + cl;
#pragma unroll
        for (int ni = 0; ni < 4; ni++) atomicAdd(dst + ni * 16, acc[mi][ni][q]);
      }
    }
  }
}

extern "C" void kernel_launch(void* const* d_in, const int* in_sizes, int n_in,
                              void* d_out, int out_size, void* d_ws, size_t ws_size,
                              hipStream_t stream) {
  const float* x  = (const float*)d_in[0];
  const float* gw = (const float*)d_in[1];
  const float* w1 = (const float*)d_in[2];
  const float* w2 = (const float*)d_in[3];
  const float* w3 = (const float*)d_in[4];
  float* out = (float*)d_out;

  char* ws = (char*)d_ws;
  u16* xb    = (u16*)ws;  ws += (size_t)TT * HH * 2;          // 8 MB
  u16* w13i  = (u16*)ws;  ws += (size_t)EE * N13 * HH * 2;    // 117 MB
  u16* w2b   = (u16*)ws;  ws += (size_t)EE * HH * FF * 2;     // 59 MB
  u16* gbuf  = (u16*)ws;  ws += (size_t)TKP * FF * 2;         // 59 MB
  int* cnt   = (int*)ws;  ws += 256;
  int* offs  = (int*)ws;  ws += 256;
  int* tok_list = (int*)ws;   ws += (size_t)EE * TT * 4;
  float* wt_list = (float*)ws; ws += (size_t)EE * TT * 4;
  int* tokp  = (int*)ws;  ws += (size_t)TKP * 4;

  const int A_SMEM = 65536 + 65536 + 1024 + 1024;   // 133120
  const int B_SMEM = 65536 + 32768 + 1024;          // 99328
  hipFuncSetAttribute((const void*)gemm_a, hipFuncAttributeMaxDynamicSharedMemorySize, A_SMEM);
  hipFuncSetAttribute((const void*)gemm_b, hipFuncAttributeMaxDynamicSharedMemorySize, B_SMEM);

  hipMemsetAsync(cnt, 0, 256, stream);
  hipMemsetAsync(out, 0, (size_t)TT * HH * 4, stream);

  cvt_w13<<<(EE * N13 * (HH / 4)) / 256, 256, 0, stream>>>(w1, w3, (ushort4*)w13i);
  cvt_w2<<<(EE * HH * (FF / 4)) / 256, 256, 0, stream>>>((const float4*)w2, (ushort4*)w2b);

  router<<<TT / 4, 256, 0, stream>>>(x, gw, cnt, tok_list, wt_list, xb);
  mk_offsets<<<1, 64, 0, stream>>>(cnt, offs);
  pairmap<<<(EE * TT) / 256, 256, 0, stream>>>(cnt, offs, tok_list, tokp);

  gemm_a<<<dim3(28, 128), 512, A_SMEM, stream>>>(xb, w13i, cnt, offs, tok_list, wt_list, gbuf);
  gemm_b<<<dim3(8, 128), 512, B_SMEM, stream>>>(gbuf, w2b, cnt, offs, tokp, out);
}

// Round 5
// 750.597 us; speedup vs baseline: 1.0113x; 1.0113x over previous
//
#include <hip/hip_runtime.h>
#include <hip/hip_bf16.h>

#define TT   4096
#define HH   1024
#define FF   3584
#define EE   8
#define N13  7168   // 2*FF (interleaved w1/w3 at 16-col granularity)
#define TKP  8192   // TT * top_k

typedef unsigned short u16;
typedef __attribute__((ext_vector_type(8))) short short8;
typedef __attribute__((ext_vector_type(4))) float floatx4;

__device__ __forceinline__ u16 f2b(float f) {
  union { float f; unsigned u; } v; v.f = f;
  unsigned r = v.u + 0x7FFFu + ((v.u >> 16) & 1u);   // RNE
  return (u16)(r >> 16);
}

// async global->LDS, 16 bytes per lane. LDS dst semantics: wave-uniform base
// + lane*16; our per-lane dst pointer equals exactly that.
__device__ __forceinline__ void gld_lds16(const u16* g, u16* l) {
  __builtin_amdgcn_global_load_lds((const __attribute__((address_space(1))) unsigned int*)g,
                                   (__attribute__((address_space(3))) unsigned int*)l,
                                   16, 0, 0);
}

#define WAIT_LGKM0() asm volatile("s_waitcnt lgkmcnt(0)" ::: "memory")
#define WAIT_VM(n)   asm volatile("s_waitcnt vmcnt(" #n ")" ::: "memory")
#define BARRIER()    do { asm volatile("" ::: "memory"); __builtin_amdgcn_s_barrier(); asm volatile("" ::: "memory"); } while (0)

// ---------------- conversions ----------------
// w13i[e][n][h]: n -> f=(n>>5)*16+(n&15), sel=(n>>4)&1 ; sel=0 -> w1[e][f], sel=1 -> w3[e][f]
__global__ __launch_bounds__(256) void cvt_w13(const float* __restrict__ w1, const float* __restrict__ w3,
                                               ushort4* __restrict__ w13i) {
  int i = blockIdx.x * 256 + threadIdx.x;      // float4 index in dest
  const int perE = N13 * (HH / 4);
  int e = i / perE;
  int rem = i - e * perE;
  int n = rem / (HH / 4);
  int h4 = rem - n * (HH / 4);
  int f = ((n >> 5) << 4) + (n & 15);
  int sel = (n >> 4) & 1;
  const float* base = sel ? w3 : w1;
  const float4* src = ((const float4*)(base + (size_t)(e * FF + f) * HH)) + h4;
  float4 v = *src;
  ushort4 o; o.x = f2b(v.x); o.y = f2b(v.y); o.z = f2b(v.z); o.w = f2b(v.w);
  w13i[i] = o;
}

__global__ __launch_bounds__(256) void cvt_w2(const float4* __restrict__ in, ushort4* __restrict__ outp) {
  int i = blockIdx.x * 256 + threadIdx.x;
  float4 v = in[i];
  ushort4 o; o.x = f2b(v.x); o.y = f2b(v.y); o.z = f2b(v.z); o.w = f2b(v.w);
  outp[i] = o;
}

// ---------------- router (fused x->bf16 conversion) ----------------
__global__ __launch_bounds__(256) void router(const float* __restrict__ x, const float* __restrict__ gw,
                                              int* __restrict__ cnt, int* __restrict__ tok_list,
                                              float* __restrict__ wt_list, u16* __restrict__ xb) {
  int lane = threadIdx.x & 63;
  int wv = threadIdx.x >> 6;
  int t = blockIdx.x * 4 + wv;
  const float* xp = x + (size_t)t * HH;
  u16* xbp = xb + (size_t)t * HH;
  float acc[EE];
#pragma unroll
  for (int e = 0; e < EE; e++) acc[e] = 0.f;
  for (int h = lane; h < HH; h += 64) {
    float xv = xp[h];
    xbp[h] = f2b(xv);
#pragma unroll
    for (int e = 0; e < EE; e++) acc[e] += xv * gw[e * HH + h];
  }
#pragma unroll
  for (int e = 0; e < EE; e++) {
#pragma unroll
    for (int off = 32; off > 0; off >>= 1) acc[e] += __shfl_xor(acc[e], off, 64);
  }
  if (lane == 0) {
    int i1 = 0;
#pragma unroll
    for (int e = 1; e < EE; e++) if (acc[e] > acc[i1]) i1 = e;
    int i2 = -1;
#pragma unroll
    for (int e = 0; e < EE; e++) {
      if (e == i1) continue;
      if (i2 < 0 || acc[e] > acc[i2]) i2 = e;
    }
    float wA = 1.f / (1.f + __expf(acc[i2] - acc[i1]));
    float wB = 1.f - wA;
    int p1 = atomicAdd(cnt + i1, 1);
    tok_list[i1 * TT + p1] = t; wt_list[i1 * TT + p1] = wA;
    int p2 = atomicAdd(cnt + i2, 1);
    tok_list[i2 * TT + p2] = t; wt_list[i2 * TT + p2] = wB;
  }
}

__global__ void mk_offsets(const int* __restrict__ cnt, int* __restrict__ offs) {
  if (threadIdx.x == 0) {
    int s = 0;
    for (int e = 0; e < EE; e++) { offs[e] = s; s += cnt[e]; }
  }
}

__global__ __launch_bounds__(256) void pairmap(const int* __restrict__ cnt, const int* __restrict__ offs,
                                               const int* __restrict__ tok_list,
                                               int* __restrict__ tokp) {
  int i = blockIdx.x * 256 + threadIdx.x;   // e*TT + s
  int e = i >> 12;
  int s = i & (TT - 1);
  if (s < cnt[e]) {
    tokp[offs[e] + s] = tok_list[i];
  }
}

// fragment-read / MFMA macros for the phased K-loop (all indices compile-time)
#define READ_AF(AFR, QM)                                                          \
  _Pragma("unroll")                                                               \
  for (int mi = 0; mi < 4; mi++) {                                                \
    AFR[mi][0] = *(const short8*)&Ab[(wr + ((QM)*4 + mi) * 16 + fr) * 64 + co0];  \
    AFR[mi][1] = *(const short8*)&Ab[(wr + ((QM)*4 + mi) * 16 + fr) * 64 + co1];  \
  }

#define READ_BF(BFR, QN)                                                          \
  _Pragma("unroll")                                                               \
  for (int ni = 0; ni < 2; ni++) {                                                \
    BFR[ni][0] = *(const short8*)&Bb[(wc + ((QN)*2 + ni) * 16 + fr) * 64 + co0];  \
    BFR[ni][1] = *(const short8*)&Bb[(wc + ((QN)*2 + ni) * 16 + fr) * 64 + co1];  \
  }

#define MFMA_QUAD(AFR, BFR, QM, QN)                                               \
  _Pragma("unroll")                                                               \
  for (int ks = 0; ks < 2; ks++)                                                  \
    _Pragma("unroll")                                                             \
    for (int mi = 0; mi < 4; mi++)                                                \
      _Pragma("unroll")                                                           \
      for (int ni = 0; ni < 2; ni++)                                              \
        acc[(QM)*4 + mi][(QN)*2 + ni] = __builtin_amdgcn_mfma_f32_16x16x32_bf16(  \
            AFR[mi][ks], BFR[ni][ks], acc[(QM)*4 + mi][(QN)*2 + ni], 0, 0, 0);

// ---------------- GEMM A + fused SwiGLU ----------------
// 256x256 tile, BK=64, 8 waves (2Mx4N), per-wave 128x64 C.
// 4-phase-per-K-tile schedule (T3+T4+T5): each phase = {ds_read fragment set
// || stage issue || 16 MFMA (one C-quadrant x K=64)} + 1 barrier.
// Ledger: B-slots of buf g&1 last read at ph2, A-slots at ph3 (lgkm0+barrier
// per phase) => staging B(g+2) at ph3 / A(g+2) at ph4 into buf g&1 is
// race-free. vmcnt(8) at group end (8 stage-instrs issued in ph3/4) =>
// K-tile g+1 (staged a full group earlier) landed; never drains to 0.
__global__ __launch_bounds__(512, 2) void gemm_a(const u16* __restrict__ xb, const u16* __restrict__ w13i,
                                                 const int* __restrict__ cnt, const int* __restrict__ offs,
                                                 const int* __restrict__ tok_list, const float* __restrict__ wt_list,
                                                 u16* __restrict__ gbuf) {
  // bijective XCD swizzle: nwg = 28*128 = 3584, 448 per XCD
  const int fid = blockIdx.y * 28 + blockIdx.x;
  const int swz = (fid & 7) * 448 + (fid >> 3);
  const int ntile = swz % 28;              // 0..27 (128 f-values each)
  const int yy = swz / 28;
  const int e = yy >> 4;
  const int rt = yy & 15;
  const int cn = cnt[e];
  if (rt * 256 >= cn) return;

  extern __shared__ char dynsmem[];
  u16* As = (u16*)dynsmem;                         // [2][256*64]
  u16* Bs = (u16*)(dynsmem + 65536);               // [2][256*64]
  int* toks = (int*)(dynsmem + 131072);            // [256]
  float* wts = (float*)(dynsmem + 131072 + 1024);  // [256]

  const int tid = threadIdx.x;
  if (tid < 256) {
    int r = rt * 256 + tid;
    if (r >= cn) r = cn - 1;
    toks[tid] = tok_list[e * TT + r];
    wts[tid] = wt_list[e * TT + r];
  }
  __syncthreads();

  // staging: round i covers rows (tid>>3)+i*64; 8 lanes per row, each 16B.
  // XOR swizzle at 16B granule: phys granule (tid&7) holds logical
  // l = (tid&7) ^ (row&7); row&7 == (tid>>3)&7 for all rounds.
  const int l = (tid & 7) ^ ((tid >> 3) & 7);
  const int dst0 = tid * 8;
  const u16* aS[4];
  const u16* bS[4];
#pragma unroll
  for (int i = 0; i < 4; i++) {
    int row = (tid >> 3) + i * 64;
    aS[i] = xb + (size_t)toks[row] * HH + l * 8;
    bS[i] = w13i + ((size_t)e * N13 + (size_t)ntile * 256 + row) * HH + l * 8;
  }

  auto STAGE_A = [&](int kt) {
    int b = (kt & 1) * 16384;
#pragma unroll
    for (int i = 0; i < 4; i++) gld_lds16(aS[i] + kt * 64, As + b + dst0 + i * 4096);
  };
  auto STAGE_B = [&](int kt) {
    int b = (kt & 1) * 16384;
#pragma unroll
    for (int i = 0; i < 4; i++) gld_lds16(bS[i] + kt * 64, Bs + b + dst0 + i * 4096);
  };

  const int lane = tid & 63;
  const int wv = tid >> 6;
  const int wr = (wv >> 2) * 128;
  const int wc = (wv & 3) * 64;
  const int fr = lane & 15;
  const int fk8 = lane >> 4;                // k-granule sub-index (0..3)
  const int co0 = ((0 + fk8) ^ (fr & 7)) * 8;   // de-swizzled 16B granule, ks=0
  const int co1 = ((4 + fk8) ^ (fr & 7)) * 8;   // ks=1

  floatx4 acc[8][4];
#pragma unroll
  for (int mi = 0; mi < 8; mi++)
#pragma unroll
    for (int ni = 0; ni < 4; ni++)
#pragma unroll
      for (int q = 0; q < 4; q++) acc[mi][ni][q] = 0.f;

  // prologue: fill both buffers (16 loads), wait for K-tile 0's 8
  STAGE_B(0); STAGE_A(0);
  STAGE_B(1); STAGE_A(1);
  WAIT_VM(8);
  BARRIER();

  short8 af[4][2], bf0[2][2], bf1[2][2];
  for (int g = 0; g < 16; g++) {
    const u16* Ab = As + (g & 1) * 16384;
    const u16* Bb = Bs + (g & 1) * 16384;
    const bool pf = (g + 2 < 16);

    // ---- phase 1: read af(qm=0)+bf0 ; MFMA quadrant (0,0)
    READ_AF(af, 0)
    READ_BF(bf0, 0)
    WAIT_LGKM0(); __builtin_amdgcn_sched_barrier(0);
    __builtin_amdgcn_s_setprio(1);
    MFMA_QUAD(af, bf0, 0, 0)
    __builtin_amdgcn_s_setprio(0);
    BARRIER();

    // ---- phase 2: read bf1 ; MFMA quadrant (0,1)
    READ_BF(bf1, 1)
    WAIT_LGKM0(); __builtin_amdgcn_sched_barrier(0);
    __builtin_amdgcn_s_setprio(1);
    MFMA_QUAD(af, bf1, 0, 1)
    __builtin_amdgcn_s_setprio(0);
    BARRIER();

    // ---- phase 3: read af(qm=1) ; stage B(g+2) (B slots free after ph2) ; MFMA (1,1)
    READ_AF(af, 1)
    if (pf) STAGE_B(g + 2);
    WAIT_LGKM0(); __builtin_amdgcn_sched_barrier(0);
    __builtin_amdgcn_s_setprio(1);
    MFMA_QUAD(af, bf1, 1, 1)
    __builtin_amdgcn_s_setprio(0);
    BARRIER();

    // ---- phase 4: stage A(g+2) (A slots free after ph3) ; MFMA (1,0) ; counted vmcnt
    if (pf) STAGE_A(g + 2);
    __builtin_amdgcn_s_setprio(1);
    MFMA_QUAD(af, bf0, 1, 0)
    __builtin_amdgcn_s_setprio(0);
    if (pf) { WAIT_VM(8); } else { WAIT_VM(0); }
    BARRIER();
  }

  // fused SwiGLU epilogue: cols (2pg, 2pg+1) are the (w1,w3) pair for
  // f = ntile*128 + wc/2 + pg*16 + (lane&15)
  const int gofs = offs[e];
  const int cl = lane & 15;
  const int qr = (lane >> 4) * 4;
#pragma unroll
  for (int mi = 0; mi < 8; mi++) {
#pragma unroll
    for (int q = 0; q < 4; q++) {
      int r = wr + mi * 16 + qr + q;
      int gr = rt * 256 + r;
      if (gr < cn) {
        float w = wts[r];
        u16* dst = gbuf + (size_t)(gofs + gr) * FF + (size_t)ntile * 128 + (wc >> 1) + cl;
#pragma unroll
        for (int pg = 0; pg < 2; pg++) {
          float h1 = acc[mi][2 * pg][q];
          float h3 = acc[mi][2 * pg + 1][q];
          float s = h1 / (1.f + __expf(-h1));
          dst[pg * 16] = f2b(s * h3 * w);
        }
      }
    }
  }
}

// ---------------- GEMM B: out[tok] += g[pair] . w2[e][h][:] ----------------
// 256x128 tile, BK=64, 8 waves (4Mx2N), per-wave 64x64 C. 2-phase pipeline, vmcnt(6).
__global__ __launch_bounds__(512, 2) void gemm_b(const u16* __restrict__ g, const u16* __restrict__ w2b,
                                                 const int* __restrict__ cnt, const int* __restrict__ offs,
                                                 const int* __restrict__ tokp, float* __restrict__ out) {
  // bijective XCD swizzle: nwg = 8*128 = 1024, 128 per XCD
  const int fid = blockIdx.y * 8 + blockIdx.x;
  const int swz = (fid & 7) * 128 + (fid >> 3);
  const int ntile = swz % 8;               // 0..7 (128 h-values each)
  const int yy = swz / 8;
  const int e = yy >> 4;
  const int rt = yy & 15;
  const int cn = cnt[e];
  if (rt * 256 >= cn) return;
  const int gofs = offs[e];

  extern __shared__ char dynsmem[];
  u16* As = (u16*)dynsmem;                  // [2][256*64]
  u16* Bs = (u16*)(dynsmem + 65536);        // [2][128*64]
  int* toks = (int*)(dynsmem + 65536 + 32768);

  const int tid = threadIdx.x;
  if (tid < 256) {
    int r = rt * 256 + tid;
    if (r >= cn) r = cn - 1;
    toks[tid] = tokp[gofs + r];
  }
  __syncthreads();

  const int l = (tid & 7) ^ ((tid >> 3) & 7);
  const int dst0 = tid * 8;
  const u16* aS[4];
  const u16* bS[2];
#pragma unroll
  for (int i = 0; i < 4; i++) {
    int row = (tid >> 3) + i * 64;
    int gr = rt * 256 + row;
    if (gr >= cn) gr = cn - 1;
    aS[i] = g + (size_t)(gofs + gr) * FF + l * 8;
  }
#pragma unroll
  for (int i = 0; i < 2; i++) {
    int row = (tid >> 3) + i * 64;
    bS[i] = w2b + ((size_t)e * HH + (size_t)ntile * 128 + row) * FF + l * 8;
  }

  auto STAGE = [&](int kt) {
    int ba = (kt & 1) * 16384;
    int bb = (kt & 1) * 8192;
#pragma unroll
    for (int i = 0; i < 4; i++) gld_lds16(aS[i] + kt * 64, As + ba + dst0 + i * 4096);
#pragma unroll
    for (int i = 0; i < 2; i++) gld_lds16(bS[i] + kt * 64, Bs + bb + dst0 + i * 4096);
  };

  const int lane = tid & 63;
  const int wv = tid >> 6;
  const int wr = (wv >> 1) * 64;
  const int wc = (wv & 1) * 64;
  const int fr = lane & 15;
  const int fk8 = lane >> 4;

  floatx4 acc[4][4];
#pragma unroll
  for (int mi = 0; mi < 4; mi++)
#pragma unroll
    for (int ni = 0; ni < 4; ni++)
#pragma unroll
      for (int q = 0; q < 4; q++) acc[mi][ni][q] = 0.f;

  STAGE(0);
  STAGE(1);
  WAIT_VM(6);
  BARRIER();

  for (int t = 0; t < 56; t++) {
    const u16* Ab = As + (t & 1) * 16384;
    const u16* Bb = Bs + (t & 1) * 8192;
    __builtin_amdgcn_s_setprio(1);
#pragma unroll
    for (int ks = 0; ks < 2; ks++) {
      const int co = ((ks * 4 + fk8) ^ (fr & 7)) * 8;
      short8 af[4];
#pragma unroll
      for (int mi = 0; mi < 4; mi++)
        af[mi] = *(const short8*)&Ab[(wr + mi * 16 + fr) * 64 + co];
#pragma unroll
      for (int ni = 0; ni < 4; ni++) {
        short8 bf = *(const short8*)&Bb[(wc + ni * 16 + fr) * 64 + co];
#pragma unroll
        for (int mi = 0; mi < 4; mi++)
          acc[mi][ni] = __builtin_amdgcn_mfma_f32_16x16x32_bf16(af[mi], bf, acc[mi][ni], 0, 0, 0);
      }
    }
    __builtin_amdgcn_s_setprio(0);
    WAIT_LGKM0();
    BARRIER();
    if (t + 2 < 56) {
      STAGE(t + 2);
      WAIT_VM(6);
    } else {
      WAIT_VM(0);
    }
    BARRIER();
  }

  const int cl = lane & 15;
  const int qr = (lane >> 4) * 4;
#pragma unroll
  for (int mi = 0; mi < 4; mi++) {
#pragma unroll
    for (int q = 0; q < 4; q++) {
      int r = wr + mi * 16 + qr + q;
      int gr = rt * 256 + r;
      if (gr < cn) {
        int tk = toks[r];
        float* dst = out + (size_t)tk * HH + (size_t)ntile * 128 + wc + cl;
#pragma unroll
        for (int ni = 0; ni < 4; ni++) atomicAdd(dst + ni * 16, acc[mi][ni][q]);
      }
    }
  }
}

extern "C" void kernel_launch(void* const* d_in, const int* in_sizes, int n_in,
                              void* d_out, int out_size, void* d_ws, size_t ws_size,
                              hipStream_t stream) {
  const float* x  = (const float*)d_in[0];
  const float* gw = (const float*)d_in[1];
  const float* w1 = (const float*)d_in[2];
  const float* w2 = (const float*)d_in[3];
  const float* w3 = (const float*)d_in[4];
  float* out = (float*)d_out;

  char* ws = (char*)d_ws;
  u16* xb    = (u16*)ws;  ws += (size_t)TT * HH * 2;          // 8 MB
  u16* w13i  = (u16*)ws;  ws += (size_t)EE * N13 * HH * 2;    // 117 MB
  u16* w2b   = (u16*)ws;  ws += (size_t)EE * HH * FF * 2;     // 59 MB
  u16* gbuf  = (u16*)ws;  ws += (size_t)TKP * FF * 2;         // 59 MB
  int* cnt   = (int*)ws;  ws += 256;
  int* offs  = (int*)ws;  ws += 256;
  int* tok_list = (int*)ws;   ws += (size_t)EE * TT * 4;
  float* wt_list = (float*)ws; ws += (size_t)EE * TT * 4;
  int* tokp  = (int*)ws;  ws += (size_t)TKP * 4;

  const int A_SMEM = 65536 + 65536 + 1024 + 1024;   // 133120
  const int B_SMEM = 65536 + 32768 + 1024;          // 99328
  hipFuncSetAttribute((const void*)gemm_a, hipFuncAttributeMaxDynamicSharedMemorySize, A_SMEM);
  hipFuncSetAttribute((const void*)gemm_b, hipFuncAttributeMaxDynamicSharedMemorySize, B_SMEM);

  hipMemsetAsync(cnt, 0, 256, stream);
  hipMemsetAsync(out, 0, (size_t)TT * HH * 4, stream);

  cvt_w13<<<(EE * N13 * (HH / 4)) / 256, 256, 0, stream>>>(w1, w3, (ushort4*)w13i);
  cvt_w2<<<(EE * HH * (FF / 4)) / 256, 256, 0, stream>>>((const float4*)w2, (ushort4*)w2b);

  router<<<TT / 4, 256, 0, stream>>>(x, gw, cnt, tok_list, wt_list, xb);
  mk_offsets<<<1, 64, 0, stream>>>(cnt, offs);
  pairmap<<<(EE * TT) / 256, 256, 0, stream>>>(cnt, offs, tok_list, tokp);

  gemm_a<<<dim3(28, 128), 512, A_SMEM, stream>>>(xb, w13i, cnt, offs, tok_list, wt_list, gbuf);
  gemm_b<<<dim3(8, 128), 512, B_SMEM, stream>>>(gbuf, w2b, cnt, offs, tokp, out);
}